// Round 11
// baseline (412.503 us; speedup 1.0000x reference)
//
#include <hip/hip_runtime.h>
#include <cstdint>

typedef _Float16 f16;
typedef _Float16 f16x8 __attribute__((ext_vector_type(8)));
typedef short s16x8 __attribute__((ext_vector_type(8)));
typedef unsigned u32x4 __attribute__((ext_vector_type(4)));
typedef float f32x4 __attribute__((ext_vector_type(4)));
typedef float floatx4 __attribute__((ext_vector_type(4)));

#define KTOT 65664      // 128*513
#define KSTEPS 2052     // KTOT/32
#define DP 544          // padded 513 -> 17*32

__device__ __forceinline__ void gload_lds16(const void* g, void* l) {
  __builtin_amdgcn_global_load_lds(
      (const __attribute__((address_space(1))) void*)g,
      (__attribute__((address_space(3))) void*)l, 16, 0, 0);
}

__device__ __forceinline__ unsigned bfpack(float e0, float e1) {
  return (__float_as_uint(e0) >> 16) | (__float_as_uint(e1) & 0xffff0000u);
}
__device__ __forceinline__ float bfhi(float x) {
  return __uint_as_float(__float_as_uint(x) & 0xffff0000u);
}

// ---------------- prep: flat bf16 hi/lo, layout [2052][pl 2][k8 4][row 128][16B] ----------------
__global__ void prep_flat(const float* __restrict__ obj_seq, char* __restrict__ flatA) {
  int o = blockIdx.x * 256 + threadIdx.x;       // grid 8208 -> o < 2052*1024 exactly
  int row = o & 127;                            // GEMM m-row = batch index
  int k8 = (o >> 7) & 3;
  int pl = (o >> 9) & 1;
  int kb = o >> 10;
  int k0 = kb * 32 + k8 * 8;
  unsigned w[4];
#pragma unroll
  for (int j = 0; j < 8; j += 2) {
    float v[2];
#pragma unroll
    for (int jj = 0; jj < 2; ++jj) {
      int k = k0 + j + jj;
      int n = k / 513;
      int d = k - n * 513;
      float x = (d < 512) ? obj_seq[(((size_t)(row << 7) + n) << 9) + d] : (float)n;
      if (pl) x = x - bfhi(x);
      v[jj] = x;
    }
    w[j >> 1] = bfpack(v[0], v[1]);
  }
  *(u32x4*)(flatA + (size_t)o * 16) = (u32x4){w[0], w[1], w[2], w[3]};
}

// ---------------- prep: objHi/objLo [B*128][544] and objT16 [B][544][128] (f16, tail path) -------
__global__ void prep_obj(const float* __restrict__ obj_seq, f16* __restrict__ objHi,
                         f16* __restrict__ objLo, f16* __restrict__ objT16) {
  __shared__ f16 tile[32][132];
  int b = blockIdx.x / 17, c = blockIdx.x - 17 * (blockIdx.x / 17);
  int t = threadIdx.x;
  if (c < 16) {
#pragma unroll
    for (int i = 0; i < 16; ++i) {
      int e = t + i * 256;
      int n = e >> 5, dd = e & 31;
      float v = obj_seq[(((size_t)(b << 7) + n) << 9) + (c << 5) + dd];
      f16 h = (f16)v;
      objHi[((size_t)((b << 7) + n)) * DP + (c << 5) + dd] = h;
      objLo[((size_t)((b << 7) + n)) * DP + (c << 5) + dd] = (f16)(v - (float)h);
      tile[dd][n] = h;
    }
    __syncthreads();
#pragma unroll
    for (int i = 0; i < 16; ++i) {
      int e = t + i * 256;
      int dd = e >> 7, n = e & 127;
      objT16[(((size_t)b * DP + (c << 5) + dd) << 7) + n] = tile[dd][n];
    }
  } else {
#pragma unroll
    for (int i = 0; i < 16; ++i) {
      int e = t + i * 256;
      int n = e >> 5, dd = e & 31;
      f16 h = (dd == 0) ? (f16)(float)n : (f16)0.f;
      objHi[((size_t)((b << 7) + n)) * DP + 512 + dd] = h;
      objLo[((size_t)((b << 7) + n)) * DP + 512 + dd] = (f16)0.f;
    }
#pragma unroll
    for (int i = 0; i < 16; ++i) {
      int e = t + i * 256;
      int dd = e >> 7, n = e & 127;
      objT16[(((size_t)b * DP + 512 + dd) << 7) + n] = (dd == 0) ? (f16)(float)n : (f16)0.f;
    }
  }
}

// ---------------- prep: W_k split (scaled by 1024) into f16 hi/lo, [64][544] ----------------
__global__ void prep_wk(const float* __restrict__ W_k, f16* __restrict__ WkHi,
                        f16* __restrict__ WkLo) {
  int o = blockIdx.x * 256 + threadIdx.x;   // < 64*544 exactly (grid 136)
  int kd = o / DP, d = o - kd * DP;
  float v = (d < 513) ? W_k[kd * 513 + d] * 1024.f : 0.f;
  f16 h = (f16)v;
  WkHi[o] = h;
  WkLo[o] = (f16)(v - (float)h);
}

// ---------------- big GEMM: per-block rotated K order (HBM channel decorrelation), ring-5 -------
// grid 256: ksp = blk&7 (== XCD), ntile = blk>>3; 1 block/CU; LDS 160KB = 5 x (A 16KB | W 16KB)
__global__ __launch_bounds__(512, 2) void qgemm(const char* __restrict__ flatA,
                                                const float* __restrict__ Wq1,
                                                const float* __restrict__ Wq2,
                                                float* __restrict__ Qpart) {
  __shared__ __align__(16) char smem[163840];   // A: 5x16KB @0 ; W: 5x16KB @81920
  const int tid = threadIdx.x;
  const int lane = tid & 63;
  const int wave = tid >> 6;
  const int wm = wave >> 2, wn = wave & 3;      // 2(m) x 4(n): wave = 64 rows x 32 cols
  const int l15 = lane & 15, lk = lane >> 4;
  const int ksp = blockIdx.x & 7;               // == XCD id (round-robin dispatch)
  const int ntile = blockIdx.x >> 3;            // 0..31
  const int t0 = (KSTEPS * ksp) >> 3;           // balanced split-K (nt = 256 or 257)
  const int nt = ((KSTEPS * (ksp + 1)) >> 3) - t0;
  const int tstart = blockIdx.x & 255;          // rotation phase; < nt always
  const float* Wsrc = (ntile < 16) ? (Wq1 + (size_t)ntile * 128 * KTOT)
                                   : (Wq2 + (size_t)(ntile - 16) * 128 * KTOT);

  // staging sources (source granule pre-XORed so LDS-linear dest == swizzled layout)
  const char* asrc = flatA + (size_t)t0 * 16384 + tid * 16;
  const float* wsrc0;
  const float* wsrc1;
  {
    int c0 = (tid >> 3), c1 = 64 + (tid >> 3);
    wsrc0 = Wsrc + (size_t)c0 * KTOT + (size_t)t0 * 32 + (((tid & 7) ^ (c0 & 7)) << 2);
    wsrc1 = Wsrc + (size_t)c1 * KTOT + (size_t)t0 * 32 + (((tid & 7) ^ (c1 & 7)) << 2);
  }

  // LDS read offsets
  int aoff[2][4];                                // [plane][mi]
#pragma unroll
  for (int pl = 0; pl < 2; ++pl)
#pragma unroll
    for (int mi = 0; mi < 4; ++mi)
      aoff[pl][mi] = pl * 8192 + lk * 2048 + (wm * 64 + mi * 16 + l15) * 16;
  int woff[2][2];                                // [nf][j]
#pragma unroll
  for (int nf = 0; nf < 2; ++nf) {
    int col = wn * 32 + nf * 16 + l15;
#pragma unroll
    for (int j = 0; j < 2; ++j)
      woff[nf][j] = col * 128 + (((2 * lk + j) ^ (col & 7)) << 4);
  }

  f32x4 acc[4][2];
#pragma unroll
  for (int mi = 0; mi < 4; ++mi)
#pragma unroll
    for (int nf = 0; nf < 2; ++nf) acc[mi][nf] = (f32x4){0.f, 0.f, 0.f, 0.f};

  auto stage = [&](int tt, int slot) {           // tt = rotated K32 index within [0, nt)
    char* SA = smem + slot * 16384;
    char* SW = smem + 81920 + slot * 16384;
    gload_lds16(asrc + (size_t)tt * 16384, SA + tid * 16);
    gload_lds16(asrc + (size_t)tt * 16384 + 8192, SA + 8192 + tid * 16);
    gload_lds16(wsrc0 + (size_t)tt * 32, SW + tid * 16);
    gload_lds16(wsrc1 + (size_t)tt * 32, SW + 8192 + tid * 16);
  };

  auto compute = [&](const char* SA, const char* SW) {
    s16x8 wH[2], wL[2];
#pragma unroll
    for (int nf = 0; nf < 2; ++nf) {
      floatx4 a = *(const floatx4*)(SW + woff[nf][0]);
      floatx4 b = *(const floatx4*)(SW + woff[nf][1]);
      u32x4 H = (u32x4){bfpack(a[0], a[1]), bfpack(a[2], a[3]),
                        bfpack(b[0], b[1]), bfpack(b[2], b[3])};
      float l0 = a[0] - bfhi(a[0]), l1 = a[1] - bfhi(a[1]);
      float l2 = a[2] - bfhi(a[2]), l3 = a[3] - bfhi(a[3]);
      float l4 = b[0] - bfhi(b[0]), l5 = b[1] - bfhi(b[1]);
      float l6 = b[2] - bfhi(b[2]), l7 = b[3] - bfhi(b[3]);
      u32x4 L = (u32x4){bfpack(l0, l1), bfpack(l2, l3), bfpack(l4, l5), bfpack(l6, l7)};
      wH[nf] = *(s16x8*)&H;
      wL[nf] = *(s16x8*)&L;
    }
    __builtin_amdgcn_s_setprio(1);
#pragma unroll
    for (int mi = 0; mi < 4; ++mi) {
      s16x8 aH = *(const s16x8*)(SA + aoff[0][mi]);
      s16x8 aL = *(const s16x8*)(SA + aoff[1][mi]);
#pragma unroll
      for (int nf = 0; nf < 2; ++nf) {
        acc[mi][nf] = __builtin_amdgcn_mfma_f32_16x16x32_bf16(aH, wH[nf], acc[mi][nf], 0, 0, 0);
        acc[mi][nf] = __builtin_amdgcn_mfma_f32_16x16x32_bf16(aH, wL[nf], acc[mi][nf], 0, 0, 0);
        acc[mi][nf] = __builtin_amdgcn_mfma_f32_16x16x32_bf16(aL, wH[nf], acc[mi][nf], 0, 0, 0);
      }
    }
    __builtin_amdgcn_s_setprio(0);
  };

  // prologue: stage rotated steps tstart..tstart+3 into slots 0..3
  {
    int tp = tstart;
#pragma unroll
    for (int k = 0; k < 4; ++k) {
      stage(tp, k);
      tp = (tp + 1 >= nt) ? 0 : tp + 1;
    }
  }

  int sl = 0, s4 = 4;
  int ts = tstart + 4; if (ts >= nt) ts -= nt;   // rotated index of stage step i+4
  for (int i = 0; i < nt; ++i) {
    // 16 outstanding -> keep 12 => stage(i) complete; genuine 3-step lead on both streams
    asm volatile("s_waitcnt vmcnt(12)" ::: "memory");
    __builtin_amdgcn_s_barrier();
    __builtin_amdgcn_sched_barrier(0);
    stage(ts, s4);                               // near wrap this re-stages consumed steps; never computed
    ts = (ts + 1 >= nt) ? 0 : ts + 1;
    __builtin_amdgcn_sched_barrier(0);
    compute(smem + sl * 16384, smem + 81920 + sl * 16384);
    sl = (sl == 4) ? 0 : sl + 1;
    s4 = (s4 == 4) ? 0 : s4 + 1;
  }
  asm volatile("s_waitcnt vmcnt(0)" ::: "memory");

  float* qout = Qpart + (size_t)ksp * 524288;
#pragma unroll
  for (int mi = 0; mi < 4; ++mi) {
    int row = wm * 64 + mi * 16 + lk * 4;
#pragma unroll
    for (int nf = 0; nf < 2; ++nf) {
      int col = ntile * 128 + wn * 32 + nf * 16 + l15;
#pragma unroll
      for (int j = 0; j < 4; ++j)
        qout[(size_t)(row + j) * 4096 + col] = acc[mi][nf][j];
    }
  }
}

// ---------------- fused tail: K-proj, scores, softmax, E, output (one block per batch) ----------
__global__ __launch_bounds__(512, 1) void predinet_tail(
    const f16* __restrict__ objHi, const f16* __restrict__ objLo, const f16* __restrict__ objT16,
    const f16* __restrict__ WkHi, const f16* __restrict__ WkLo,
    const float* __restrict__ Qpart, const float* __restrict__ W_s, float* __restrict__ out) {
  __shared__ __align__(16) char smem[105984];
  const int b = blockIdx.x;
  const int tid = threadIdx.x, lane = tid & 63, wave = tid >> 6;
  const int l15 = lane & 15, lk = lane >> 4;

  f16* WT = (f16*)(smem);               // [64][136] weights^T; later Ws16 [16][544]
  f16* Qh = (f16*)(smem + 17408);       // [64][72]
  f16* Ql = (f16*)(smem + 26624);       // [64][72]
  f16* Kh = (f16*)(smem + 35840);       // [128][72]
  f16* Kl = (f16*)(smem + 54272);       // [128][72]
  float* S = (float*)(smem + 72704);    // [128][65]
  f16* E = (f16*)(smem + 17408);        // [544][73]  (aliases Qh..S-head after P3)
  float* DL = (float*)(smem + 96832);   // [16][64]

  // P0: sum 8 split-K partials, stage Q[b] fp32 -> hi/lo f16
  {
    const float* qp = Qpart + (size_t)b * 4096 + tid * 8;
    floatx4 q0 = (floatx4){0.f, 0.f, 0.f, 0.f};
    floatx4 q1 = (floatx4){0.f, 0.f, 0.f, 0.f};
#pragma unroll
    for (int p = 0; p < 8; ++p) {
      q0 += *(const floatx4*)(qp + (size_t)p * 524288);
      q1 += *(const floatx4*)(qp + (size_t)p * 524288 + 4);
    }
    int hp = tid >> 3, kd = (tid * 8) & 63;
    f16x8 vh, vl;
#pragma unroll
    for (int j = 0; j < 4; ++j) {
      f16 h0 = (f16)q0[j]; vh[j] = h0; vl[j] = (f16)(q0[j] - (float)h0);
      f16 h1 = (f16)q1[j]; vh[4 + j] = h1; vl[4 + j] = (f16)(q1[j] - (float)h1);
    }
    *(f16x8*)(Qh + hp * 72 + kd) = vh;
    *(f16x8*)(Ql + hp * 72 + kd) = vl;
  }
  // P1: K-GEMM  K[n][kd] = obj @ Wk^T (3-term split), hi/lo f16 out
  {
    f32x4 acc[4];
#pragma unroll
    for (int nf = 0; nf < 4; ++nf) acc[nf] = (f32x4){0.f, 0.f, 0.f, 0.f};
    const f16* arowH = objHi + ((size_t)(b * 128) + wave * 16 + l15) * DP + lk * 8;
    const f16* arowL = objLo + ((size_t)(b * 128) + wave * 16 + l15) * DP + lk * 8;
    const f16* bhi = WkHi + (size_t)l15 * DP + lk * 8;
    const f16* blo = WkLo + (size_t)l15 * DP + lk * 8;
    for (int ks = 0; ks < 17; ++ks) {
      f16x8 ah = *(const f16x8*)(arowH + ks * 32);
      f16x8 al = *(const f16x8*)(arowL + ks * 32);
#pragma unroll
      for (int nf = 0; nf < 4; ++nf) {
        f16x8 h = *(const f16x8*)(bhi + (size_t)nf * 16 * DP + ks * 32);
        f16x8 l = *(const f16x8*)(blo + (size_t)nf * 16 * DP + ks * 32);
        acc[nf] = __builtin_amdgcn_mfma_f32_16x16x32_f16(ah, h, acc[nf], 0, 0, 0);
        acc[nf] = __builtin_amdgcn_mfma_f32_16x16x32_f16(ah, l, acc[nf], 0, 0, 0);
        acc[nf] = __builtin_amdgcn_mfma_f32_16x16x32_f16(al, h, acc[nf], 0, 0, 0);
      }
    }
#pragma unroll
    for (int nf = 0; nf < 4; ++nf)
#pragma unroll
      for (int j = 0; j < 4; ++j) {
        float kv = acc[nf][j] * (1.f / 1024.f);
        f16 h = (f16)kv;
        Kh[(wave * 16 + lk * 4 + j) * 72 + nf * 16 + l15] = h;
        Kl[(wave * 16 + lk * 4 + j) * 72 + nf * 16 + l15] = (f16)(kv - (float)h);
      }
  }
  __syncthreads();
  // P2: scores S[n][h'] = K @ Q^T (3-term split, fp32 out)
  {
    f32x4 acc[4];
#pragma unroll
    for (int nf = 0; nf < 4; ++nf) acc[nf] = (f32x4){0.f, 0.f, 0.f, 0.f};
#pragma unroll
    for (int ks = 0; ks < 2; ++ks) {
      f16x8 ah = *(const f16x8*)(Kh + (wave * 16 + l15) * 72 + ks * 32 + lk * 8);
      f16x8 al = *(const f16x8*)(Kl + (wave * 16 + l15) * 72 + ks * 32 + lk * 8);
#pragma unroll
      for (int nf = 0; nf < 4; ++nf) {
        f16x8 bh = *(const f16x8*)(Qh + (nf * 16 + l15) * 72 + ks * 32 + lk * 8);
        f16x8 bl = *(const f16x8*)(Ql + (nf * 16 + l15) * 72 + ks * 32 + lk * 8);
        acc[nf] = __builtin_amdgcn_mfma_f32_16x16x32_f16(ah, bh, acc[nf], 0, 0, 0);
        acc[nf] = __builtin_amdgcn_mfma_f32_16x16x32_f16(ah, bl, acc[nf], 0, 0, 0);
        acc[nf] = __builtin_amdgcn_mfma_f32_16x16x32_f16(al, bh, acc[nf], 0, 0, 0);
      }
    }
#pragma unroll
    for (int nf = 0; nf < 4; ++nf)
#pragma unroll
      for (int j = 0; j < 4; ++j)
        S[(wave * 16 + lk * 4 + j) * 65 + nf * 16 + l15] = acc[nf][j];
  }
  __syncthreads();
  // P3: softmax over n (wave-parallel, 8 columns per wave); weights -> WT[h'][n] f16
  {
#pragma unroll
    for (int ci = 0; ci < 8; ++ci) {
      int c = wave * 8 + ci;
      float s0 = S[lane * 65 + c], s1 = S[(lane + 64) * 65 + c];
      float m = fmaxf(s0, s1);
      for (int off = 32; off; off >>= 1) m = fmaxf(m, __shfl_xor(m, off));
      float e0 = __expf(s0 - m), e1 = __expf(s1 - m);
      float sum = e0 + e1;
      for (int off = 32; off; off >>= 1) sum += __shfl_xor(sum, off);
      float inv = 1.f / sum;
      WT[c * 136 + lane] = (f16)(e0 * inv);
      WT[c * 136 + 64 + lane] = (f16)(e1 * inv);
    }
  }
  __syncthreads();
  // P4: E^T[d][h'] = obj^T @ weights  (f16 MFMA, fp32 accum, f16 store)
  {
    f16x8 bw[4][4];
#pragma unroll
    for (int nf = 0; nf < 4; ++nf)
#pragma unroll
      for (int ks = 0; ks < 4; ++ks)
        bw[nf][ks] = *(const f16x8*)(WT + (nf * 16 + l15) * 136 + ks * 32 + lk * 8);
    for (int r = 0; r < 5; ++r) {
      int mi = r * 8 + wave;
      if (mi >= 34) break;
      const f16* arow = objT16 + (((size_t)b * DP + mi * 16 + l15) << 7) + lk * 8;
      f16x8 a[4];
#pragma unroll
      for (int ks = 0; ks < 4; ++ks) a[ks] = *(const f16x8*)(arow + ks * 32);
#pragma unroll
      for (int nf = 0; nf < 4; ++nf) {
        f32x4 acc = (f32x4){0.f, 0.f, 0.f, 0.f};
#pragma unroll
        for (int ks = 0; ks < 4; ++ks)
          acc = __builtin_amdgcn_mfma_f32_16x16x32_f16(a[ks], bw[nf][ks], acc, 0, 0, 0);
#pragma unroll
        for (int j = 0; j < 4; ++j)
          E[(mi * 16 + lk * 4 + j) * 73 + nf * 16 + l15] = (f16)acc[j];
      }
    }
  }
  __syncthreads();
  // P5a: W_s -> f16 [16][544] (reuses WT region)
  {
    f16* Ws16 = WT;
    for (int i = tid; i < 16 * DP; i += 512) {
      int r = i / DP, d = i - r * DP;
      Ws16[i] = (f16)((d < 513) ? W_s[r * 513 + d] : 0.f);
    }
  }
  __syncthreads();
  // P5b: DL[r][h'] = sum_d E[d][h'] * Ws[r][d]
  if (wave < 4) {
    const f16* Ws16 = WT;
    f32x4 acc = (f32x4){0.f, 0.f, 0.f, 0.f};
    for (int ks = 0; ks < 17; ++ks) {
      f16x8 a = *(const f16x8*)(Ws16 + l15 * DP + ks * 32 + lk * 8);
      f16x8 bv;
#pragma unroll
      for (int jj = 0; jj < 8; ++jj)
        bv[jj] = E[(ks * 32 + lk * 8 + jj) * 73 + wave * 16 + l15];
      acc = __builtin_amdgcn_mfma_f32_16x16x32_f16(a, bv, acc, 0, 0, 0);
    }
#pragma unroll
    for (int j = 0; j < 4; ++j) DL[(lk * 4 + j) * 64 + wave * 16 + l15] = acc[j];
  }
  __syncthreads();
  // P5c: write output [b][h*18 + r], plus tag channels 16/17
  {
    int h = tid >> 4, r = tid & 15;
    float v = DL[r * 64 + h] - DL[r * 64 + 32 + h];
    out[(size_t)b * 576 + h * 18 + r] = v;
    if (tid < 64) {
      int set = tid >> 5, hh = tid & 31;
      out[(size_t)b * 576 + hh * 18 + 16 + set] = (float)E[512 * 73 + set * 32 + hh];
    }
  }
}

extern "C" void kernel_launch(void* const* d_in, const int* in_sizes, int n_in,
                              void* d_out, int out_size, void* d_ws, size_t ws_size,
                              hipStream_t stream) {
  const float* obj_seq = (const float*)d_in[0];
  const float* W_k = (const float*)d_in[1];
  const float* W_q1 = (const float*)d_in[2];
  const float* W_q2 = (const float*)d_in[3];
  const float* W_s = (const float*)d_in[4];
  float* out = (float*)d_out;

  char* ws = (char*)d_ws;
  size_t off = 0;
  auto carve = [&](size_t bytes) -> char* {
    char* p = ws + off;
    off += (bytes + 255) & ~(size_t)255;
    return p;
  };
  char* flatA = carve((size_t)KSTEPS * 16384);             // 33.6 MB (bf16 hi/lo planes)
  f16* objHi = (f16*)carve((size_t)16384 * DP * 2);        // 17.8 MB
  f16* objLo = (f16*)carve((size_t)16384 * DP * 2);        // 17.8 MB
  f16* objT16 = (f16*)carve((size_t)128 * DP * 128 * 2);   // 17.8 MB
  f16* WkHi = (f16*)carve((size_t)64 * DP * 2);
  f16* WkLo = (f16*)carve((size_t)64 * DP * 2);
  float* Qpart = (float*)carve((size_t)8 * 524288 * 4);    // 16 MB
  (void)ws_size; (void)in_sizes; (void)n_in; (void)out_size;

  prep_flat<<<8208, 256, 0, stream>>>(obj_seq, flatA);
  prep_obj<<<2176, 256, 0, stream>>>(obj_seq, objHi, objLo, objT16);
  prep_wk<<<136, 256, 0, stream>>>(W_k, WkHi, WkLo);
  qgemm<<<256, 512, 0, stream>>>(flatA, W_q1, W_q2, Qpart);
  predinet_tail<<<128, 512, 0, stream>>>(objHi, objLo, objT16, WkHi, WkLo, Qpart, W_s, out);
}

// Round 12
// 350.185 us; speedup vs baseline: 1.1780x; 1.1780x over previous
//
#include <hip/hip_runtime.h>
#include <cstdint>

typedef _Float16 f16;
typedef _Float16 f16x8 __attribute__((ext_vector_type(8)));
typedef short s16x8 __attribute__((ext_vector_type(8)));
typedef unsigned u32x4 __attribute__((ext_vector_type(4)));
typedef float f32x4 __attribute__((ext_vector_type(4)));
typedef float floatx4 __attribute__((ext_vector_type(4)));

#define KTOT 65664      // 128*513
#define KSTEPS 2052     // KTOT/32
#define DP 544          // padded 513 -> 17*32

__device__ __forceinline__ void gload_lds16(const void* g, void* l) {
  __builtin_amdgcn_global_load_lds(
      (const __attribute__((address_space(1))) void*)g,
      (__attribute__((address_space(3))) void*)l, 16, 0, 0);
}

__device__ __forceinline__ unsigned bfpack(float e0, float e1) {
  return (__float_as_uint(e0) >> 16) | (__float_as_uint(e1) & 0xffff0000u);
}
__device__ __forceinline__ float bfhi(float x) {
  return __uint_as_float(__float_as_uint(x) & 0xffff0000u);
}

// ---------------- prep: flat bf16 hi/lo, layout [2052][pl 2][k8 4][row 128][16B] ----------------
__global__ void prep_flat(const float* __restrict__ obj_seq, char* __restrict__ flatA) {
  int o = blockIdx.x * 256 + threadIdx.x;       // grid 8208 -> o < 2052*1024 exactly
  int row = o & 127;                            // GEMM m-row = batch index
  int k8 = (o >> 7) & 3;
  int pl = (o >> 9) & 1;
  int kb = o >> 10;
  int k0 = kb * 32 + k8 * 8;
  unsigned w[4];
#pragma unroll
  for (int j = 0; j < 8; j += 2) {
    float v[2];
#pragma unroll
    for (int jj = 0; jj < 2; ++jj) {
      int k = k0 + j + jj;
      int n = k / 513;
      int d = k - n * 513;
      float x = (d < 512) ? obj_seq[(((size_t)(row << 7) + n) << 9) + d] : (float)n;
      if (pl) x = x - bfhi(x);
      v[jj] = x;
    }
    w[j >> 1] = bfpack(v[0], v[1]);
  }
  *(u32x4*)(flatA + (size_t)o * 16) = (u32x4){w[0], w[1], w[2], w[3]};
}

// ---------------- prep: objHi/objLo [B*128][544] and objT16 [B][544][128] (f16, tail path) -------
__global__ void prep_obj(const float* __restrict__ obj_seq, f16* __restrict__ objHi,
                         f16* __restrict__ objLo, f16* __restrict__ objT16) {
  __shared__ f16 tile[32][132];
  int b = blockIdx.x / 17, c = blockIdx.x - 17 * (blockIdx.x / 17);
  int t = threadIdx.x;
  if (c < 16) {
#pragma unroll
    for (int i = 0; i < 16; ++i) {
      int e = t + i * 256;
      int n = e >> 5, dd = e & 31;
      float v = obj_seq[(((size_t)(b << 7) + n) << 9) + (c << 5) + dd];
      f16 h = (f16)v;
      objHi[((size_t)((b << 7) + n)) * DP + (c << 5) + dd] = h;
      objLo[((size_t)((b << 7) + n)) * DP + (c << 5) + dd] = (f16)(v - (float)h);
      tile[dd][n] = h;
    }
    __syncthreads();
#pragma unroll
    for (int i = 0; i < 16; ++i) {
      int e = t + i * 256;
      int dd = e >> 7, n = e & 127;
      objT16[(((size_t)b * DP + (c << 5) + dd) << 7) + n] = tile[dd][n];
    }
  } else {
#pragma unroll
    for (int i = 0; i < 16; ++i) {
      int e = t + i * 256;
      int n = e >> 5, dd = e & 31;
      f16 h = (dd == 0) ? (f16)(float)n : (f16)0.f;
      objHi[((size_t)((b << 7) + n)) * DP + 512 + dd] = h;
      objLo[((size_t)((b << 7) + n)) * DP + 512 + dd] = (f16)0.f;
    }
#pragma unroll
    for (int i = 0; i < 16; ++i) {
      int e = t + i * 256;
      int dd = e >> 7, n = e & 127;
      objT16[(((size_t)b * DP + 512 + dd) << 7) + n] = (dd == 0) ? (f16)(float)n : (f16)0.f;
    }
  }
}

// ---------------- prep: W_k split (scaled by 1024) into f16 hi/lo, [64][544] ----------------
__global__ void prep_wk(const float* __restrict__ W_k, f16* __restrict__ WkHi,
                        f16* __restrict__ WkLo) {
  int o = blockIdx.x * 256 + threadIdx.x;   // < 64*544 exactly (grid 136)
  int kd = o / DP, d = o - kd * DP;
  float v = (d < 513) ? W_k[kd * 513 + d] * 1024.f : 0.f;
  f16 h = (f16)v;
  WkHi[o] = h;
  WkLo[o] = (f16)(v - (float)h);
}

// ---------------- big GEMM: 128x256 tile, ring-3 A+W, SINGLE barrier/step, counted vmcnt ----------
// grid 256 = ntile(16) x ksp(16); 1 block/CU; LDS 144KB: A 3x16KB @0, W 3x32KB @49152
__global__ __launch_bounds__(512, 2) void qgemm(const char* __restrict__ flatA,
                                                const float* __restrict__ Wq1,
                                                const float* __restrict__ Wq2,
                                                float* __restrict__ Qpart) {
  __shared__ __align__(16) char smem[147456];
  const int tid = threadIdx.x;
  const int lane = tid & 63;
  const int wave = tid >> 6;
  const int wm = wave >> 2, wn = wave & 3;      // 2(m) x 4(n): wave owns 64 rows x 64 cols
  const int l15 = lane & 15, lk = lane >> 4;
  const int ntile = blockIdx.x & 15;
  const int ksp = blockIdx.x >> 4;              // 0..15
  const int t0 = ksp * 129;                     // K32 units
  const int nt = min(129, KSTEPS - t0);
  const float* Wsrc = (ntile < 8) ? (Wq1 + (size_t)ntile * 256 * KTOT)
                                  : (Wq2 + (size_t)(ntile - 8) * 256 * KTOT);

  // staging sources
  const char* asrc = flatA + (size_t)t0 * 16384 + tid * 16;   // +pl*8192, +t*16384
  const float* wsrcs[4];
#pragma unroll
  for (int c = 0; c < 4; ++c) {
    int col = c * 64 + (tid >> 3);
    int gs = (tid & 7) ^ (col & 7);
    wsrcs[c] = Wsrc + (size_t)col * KTOT + (size_t)t0 * 32 + gs * 4;
  }

  // LDS read offsets (within a slot)
  int aoff[2][4];                                // [plane][mi]
#pragma unroll
  for (int pl = 0; pl < 2; ++pl)
#pragma unroll
    for (int mi = 0; mi < 4; ++mi)
      aoff[pl][mi] = pl * 8192 + lk * 2048 + (wm * 64 + mi * 16 + l15) * 16;
  int woff[4][2];                                // [nf][j]
#pragma unroll
  for (int nf = 0; nf < 4; ++nf) {
    int col = wn * 64 + nf * 16 + l15;
#pragma unroll
    for (int j = 0; j < 2; ++j)
      woff[nf][j] = col * 128 + (((2 * lk + j) ^ (col & 7)) << 4);
  }

  f32x4 acc[4][4];
#pragma unroll
  for (int mi = 0; mi < 4; ++mi)
#pragma unroll
    for (int nf = 0; nf < 4; ++nf) acc[mi][nf] = (f32x4){0.f, 0.f, 0.f, 0.f};

  auto stageW = [&](int tt, int slot) {
    char* S = smem + 49152 + slot * 32768;
#pragma unroll
    for (int c = 0; c < 4; ++c)
      gload_lds16(wsrcs[c] + (size_t)tt * 32, S + c * 8192 + tid * 16);
  };
  auto stageA = [&](int tt, int slot) {
    char* S = smem + slot * 16384;
    gload_lds16(asrc + (size_t)tt * 16384, S + tid * 16);
    gload_lds16(asrc + (size_t)tt * 16384 + 8192, S + 8192 + tid * 16);
  };

  auto compute = [&](const char* SA, const char* SW) {
    s16x8 wH[4], wL[4];
#pragma unroll
    for (int nf = 0; nf < 4; ++nf) {
      floatx4 a = *(const floatx4*)(SW + woff[nf][0]);
      floatx4 b = *(const floatx4*)(SW + woff[nf][1]);
      u32x4 H = (u32x4){bfpack(a[0], a[1]), bfpack(a[2], a[3]),
                        bfpack(b[0], b[1]), bfpack(b[2], b[3])};
      float l0 = a[0] - bfhi(a[0]), l1 = a[1] - bfhi(a[1]);
      float l2 = a[2] - bfhi(a[2]), l3 = a[3] - bfhi(a[3]);
      float l4 = b[0] - bfhi(b[0]), l5 = b[1] - bfhi(b[1]);
      float l6 = b[2] - bfhi(b[2]), l7 = b[3] - bfhi(b[3]);
      u32x4 L = (u32x4){bfpack(l0, l1), bfpack(l2, l3), bfpack(l4, l5), bfpack(l6, l7)};
      wH[nf] = *(s16x8*)&H;
      wL[nf] = *(s16x8*)&L;
    }
    __builtin_amdgcn_s_setprio(1);
#pragma unroll
    for (int mi = 0; mi < 4; ++mi) {
      s16x8 aH = *(const s16x8*)(SA + aoff[0][mi]);
      s16x8 aL = *(const s16x8*)(SA + aoff[1][mi]);
#pragma unroll
      for (int nf = 0; nf < 4; ++nf) {
        acc[mi][nf] = __builtin_amdgcn_mfma_f32_16x16x32_bf16(aH, wH[nf], acc[mi][nf], 0, 0, 0);
        acc[mi][nf] = __builtin_amdgcn_mfma_f32_16x16x32_bf16(aH, wL[nf], acc[mi][nf], 0, 0, 0);
        acc[mi][nf] = __builtin_amdgcn_mfma_f32_16x16x32_bf16(aL, wH[nf], acc[mi][nf], 0, 0, 0);
      }
    }
    __builtin_amdgcn_s_setprio(0);
  };

  // prologue: 2 tiles in flight (oldest-first: W0,A0,W1,A1 = 12 vm-ops/thread)
  stageW(0, 0); stageA(0, 0);
  stageW(1, 1); stageA(1, 1);

  int sl = 0;
  for (int t = 0; t < nt; ++t) {
    if (t < nt - 2) asm volatile("s_waitcnt vmcnt(6)" ::: "memory");
    else            asm volatile("s_waitcnt vmcnt(0)" ::: "memory");
    __builtin_amdgcn_s_barrier();
    __builtin_amdgcn_sched_barrier(0);
    int s2 = sl + 2; if (s2 >= 3) s2 -= 3;
    if (t + 2 < nt) stageW(t + 2, s2);          // early: 2 steps of HBM lead
    __builtin_amdgcn_sched_barrier(0);
    compute(smem + sl * 16384, smem + 49152 + sl * 32768);
    if (t + 2 < nt) stageA(t + 2, s2);          // A is L3-resident; late issue ok
    sl = (sl == 2) ? 0 : sl + 1;
  }

  float* qout = Qpart + (size_t)ksp * 524288;
#pragma unroll
  for (int mi = 0; mi < 4; ++mi) {
    int row = wm * 64 + mi * 16 + lk * 4;
#pragma unroll
    for (int nf = 0; nf < 4; ++nf) {
      int col = ntile * 256 + wn * 64 + nf * 16 + l15;
#pragma unroll
      for (int j = 0; j < 4; ++j)
        qout[(size_t)(row + j) * 4096 + col] = acc[mi][nf][j];
    }
  }
}

// ---------------- fused tail: K-proj, scores, softmax, E, output (one block per batch) ----------
__global__ __launch_bounds__(512, 1) void predinet_tail(
    const f16* __restrict__ objHi, const f16* __restrict__ objLo, const f16* __restrict__ objT16,
    const f16* __restrict__ WkHi, const f16* __restrict__ WkLo,
    const float* __restrict__ Qpart, const float* __restrict__ W_s, float* __restrict__ out) {
  __shared__ __align__(16) char smem[105984];
  const int b = blockIdx.x;
  const int tid = threadIdx.x, lane = tid & 63, wave = tid >> 6;
  const int l15 = lane & 15, lk = lane >> 4;

  f16* WT = (f16*)(smem);               // [64][136] weights^T; later Ws16 [16][544]
  f16* Qh = (f16*)(smem + 17408);       // [64][72]
  f16* Ql = (f16*)(smem + 26624);       // [64][72]
  f16* Kh = (f16*)(smem + 35840);       // [128][72]
  f16* Kl = (f16*)(smem + 54272);       // [128][72]
  float* S = (float*)(smem + 72704);    // [128][65]
  f16* E = (f16*)(smem + 17408);        // [544][73]  (aliases Qh..S-head after P3)
  float* DL = (float*)(smem + 96832);   // [16][64]

  // P0: sum 16 split-K partials, stage Q[b] fp32 -> hi/lo f16
  {
    const float* qp = Qpart + (size_t)b * 4096 + tid * 8;
    floatx4 q0 = (floatx4){0.f, 0.f, 0.f, 0.f};
    floatx4 q1 = (floatx4){0.f, 0.f, 0.f, 0.f};
#pragma unroll
    for (int p = 0; p < 16; ++p) {
      q0 += *(const floatx4*)(qp + (size_t)p * 524288);
      q1 += *(const floatx4*)(qp + (size_t)p * 524288 + 4);
    }
    int hp = tid >> 3, kd = (tid * 8) & 63;
    f16x8 vh, vl;
#pragma unroll
    for (int j = 0; j < 4; ++j) {
      f16 h0 = (f16)q0[j]; vh[j] = h0; vl[j] = (f16)(q0[j] - (float)h0);
      f16 h1 = (f16)q1[j]; vh[4 + j] = h1; vl[4 + j] = (f16)(q1[j] - (float)h1);
    }
    *(f16x8*)(Qh + hp * 72 + kd) = vh;
    *(f16x8*)(Ql + hp * 72 + kd) = vl;
  }
  // P1: K-GEMM  K[n][kd] = obj @ Wk^T (3-term split), hi/lo f16 out
  {
    f32x4 acc[4];
#pragma unroll
    for (int nf = 0; nf < 4; ++nf) acc[nf] = (f32x4){0.f, 0.f, 0.f, 0.f};
    const f16* arowH = objHi + ((size_t)(b * 128) + wave * 16 + l15) * DP + lk * 8;
    const f16* arowL = objLo + ((size_t)(b * 128) + wave * 16 + l15) * DP + lk * 8;
    const f16* bhi = WkHi + (size_t)l15 * DP + lk * 8;
    const f16* blo = WkLo + (size_t)l15 * DP + lk * 8;
    for (int ks = 0; ks < 17; ++ks) {
      f16x8 ah = *(const f16x8*)(arowH + ks * 32);
      f16x8 al = *(const f16x8*)(arowL + ks * 32);
#pragma unroll
      for (int nf = 0; nf < 4; ++nf) {
        f16x8 h = *(const f16x8*)(bhi + (size_t)nf * 16 * DP + ks * 32);
        f16x8 l = *(const f16x8*)(blo + (size_t)nf * 16 * DP + ks * 32);
        acc[nf] = __builtin_amdgcn_mfma_f32_16x16x32_f16(ah, h, acc[nf], 0, 0, 0);
        acc[nf] = __builtin_amdgcn_mfma_f32_16x16x32_f16(ah, l, acc[nf], 0, 0, 0);
        acc[nf] = __builtin_amdgcn_mfma_f32_16x16x32_f16(al, h, acc[nf], 0, 0, 0);
      }
    }
#pragma unroll
    for (int nf = 0; nf < 4; ++nf)
#pragma unroll
      for (int j = 0; j < 4; ++j) {
        float kv = acc[nf][j] * (1.f / 1024.f);
        f16 h = (f16)kv;
        Kh[(wave * 16 + lk * 4 + j) * 72 + nf * 16 + l15] = h;
        Kl[(wave * 16 + lk * 4 + j) * 72 + nf * 16 + l15] = (f16)(kv - (float)h);
      }
  }
  __syncthreads();
  // P2: scores S[n][h'] = K @ Q^T (3-term split, fp32 out)
  {
    f32x4 acc[4];
#pragma unroll
    for (int nf = 0; nf < 4; ++nf) acc[nf] = (f32x4){0.f, 0.f, 0.f, 0.f};
#pragma unroll
    for (int ks = 0; ks < 2; ++ks) {
      f16x8 ah = *(const f16x8*)(Kh + (wave * 16 + l15) * 72 + ks * 32 + lk * 8);
      f16x8 al = *(const f16x8*)(Kl + (wave * 16 + l15) * 72 + ks * 32 + lk * 8);
#pragma unroll
      for (int nf = 0; nf < 4; ++nf) {
        f16x8 bh = *(const f16x8*)(Qh + (nf * 16 + l15) * 72 + ks * 32 + lk * 8);
        f16x8 bl = *(const f16x8*)(Ql + (nf * 16 + l15) * 72 + ks * 32 + lk * 8);
        acc[nf] = __builtin_amdgcn_mfma_f32_16x16x32_f16(ah, bh, acc[nf], 0, 0, 0);
        acc[nf] = __builtin_amdgcn_mfma_f32_16x16x32_f16(ah, bl, acc[nf], 0, 0, 0);
        acc[nf] = __builtin_amdgcn_mfma_f32_16x16x32_f16(al, bh, acc[nf], 0, 0, 0);
      }
    }
#pragma unroll
    for (int nf = 0; nf < 4; ++nf)
#pragma unroll
      for (int j = 0; j < 4; ++j)
        S[(wave * 16 + lk * 4 + j) * 65 + nf * 16 + l15] = acc[nf][j];
  }
  __syncthreads();
  // P3: softmax over n (wave-parallel, 8 columns per wave); weights -> WT[h'][n] f16
  {
#pragma unroll
    for (int ci = 0; ci < 8; ++ci) {
      int c = wave * 8 + ci;
      float s0 = S[lane * 65 + c], s1 = S[(lane + 64) * 65 + c];
      float m = fmaxf(s0, s1);
      for (int off = 32; off; off >>= 1) m = fmaxf(m, __shfl_xor(m, off));
      float e0 = __expf(s0 - m), e1 = __expf(s1 - m);
      float sum = e0 + e1;
      for (int off = 32; off; off >>= 1) sum += __shfl_xor(sum, off);
      float inv = 1.f / sum;
      WT[c * 136 + lane] = (f16)(e0 * inv);
      WT[c * 136 + 64 + lane] = (f16)(e1 * inv);
    }
  }
  __syncthreads();
  // P4: E^T[d][h'] = obj^T @ weights  (f16 MFMA, fp32 accum, f16 store)
  {
    f16x8 bw[4][4];
#pragma unroll
    for (int nf = 0; nf < 4; ++nf)
#pragma unroll
      for (int ks = 0; ks < 4; ++ks)
        bw[nf][ks] = *(const f16x8*)(WT + (nf * 16 + l15) * 136 + ks * 32 + lk * 8);
    for (int r = 0; r < 5; ++r) {
      int mi = r * 8 + wave;
      if (mi >= 34) break;
      const f16* arow = objT16 + (((size_t)b * DP + mi * 16 + l15) << 7) + lk * 8;
      f16x8 a[4];
#pragma unroll
      for (int ks = 0; ks < 4; ++ks) a[ks] = *(const f16x8*)(arow + ks * 32);
#pragma unroll
      for (int nf = 0; nf < 4; ++nf) {
        f32x4 acc = (f32x4){0.f, 0.f, 0.f, 0.f};
#pragma unroll
        for (int ks = 0; ks < 4; ++ks)
          acc = __builtin_amdgcn_mfma_f32_16x16x32_f16(a[ks], bw[nf][ks], acc, 0, 0, 0);
#pragma unroll
        for (int j = 0; j < 4; ++j)
          E[(mi * 16 + lk * 4 + j) * 73 + nf * 16 + l15] = (f16)acc[j];
      }
    }
  }
  __syncthreads();
  // P5a: W_s -> f16 [16][544] (reuses WT region)
  {
    f16* Ws16 = WT;
    for (int i = tid; i < 16 * DP; i += 512) {
      int r = i / DP, d = i - r * DP;
      Ws16[i] = (f16)((d < 513) ? W_s[r * 513 + d] : 0.f);
    }
  }
  __syncthreads();
  // P5b: DL[r][h'] = sum_d E[d][h'] * Ws[r][d]
  if (wave < 4) {
    const f16* Ws16 = WT;
    f32x4 acc = (f32x4){0.f, 0.f, 0.f, 0.f};
    for (int ks = 0; ks < 17; ++ks) {
      f16x8 a = *(const f16x8*)(Ws16 + l15 * DP + ks * 32 + lk * 8);
      f16x8 bv;
#pragma unroll
      for (int jj = 0; jj < 8; ++jj)
        bv[jj] = E[(ks * 32 + lk * 8 + jj) * 73 + wave * 16 + l15];
      acc = __builtin_amdgcn_mfma_f32_16x16x32_f16(a, bv, acc, 0, 0, 0);
    }
#pragma unroll
    for (int j = 0; j < 4; ++j) DL[(lk * 4 + j) * 64 + wave * 16 + l15] = acc[j];
  }
  __syncthreads();
  // P5c: write output [b][h*18 + r], plus tag channels 16/17
  {
    int h = tid >> 4, r = tid & 15;
    float v = DL[r * 64 + h] - DL[r * 64 + 32 + h];
    out[(size_t)b * 576 + h * 18 + r] = v;
    if (tid < 64) {
      int set = tid >> 5, hh = tid & 31;
      out[(size_t)b * 576 + hh * 18 + 16 + set] = (float)E[512 * 73 + set * 32 + hh];
    }
  }
}

extern "C" void kernel_launch(void* const* d_in, const int* in_sizes, int n_in,
                              void* d_out, int out_size, void* d_ws, size_t ws_size,
                              hipStream_t stream) {
  const float* obj_seq = (const float*)d_in[0];
  const float* W_k = (const float*)d_in[1];
  const float* W_q1 = (const float*)d_in[2];
  const float* W_q2 = (const float*)d_in[3];
  const float* W_s = (const float*)d_in[4];
  float* out = (float*)d_out;

  char* ws = (char*)d_ws;
  size_t off = 0;
  auto carve = [&](size_t bytes) -> char* {
    char* p = ws + off;
    off += (bytes + 255) & ~(size_t)255;
    return p;
  };
  char* flatA = carve((size_t)KSTEPS * 16384);             // 33.6 MB (bf16 hi/lo planes)
  f16* objHi = (f16*)carve((size_t)16384 * DP * 2);        // 17.8 MB
  f16* objLo = (f16*)carve((size_t)16384 * DP * 2);        // 17.8 MB
  f16* objT16 = (f16*)carve((size_t)128 * DP * 128 * 2);   // 17.8 MB
  f16* WkHi = (f16*)carve((size_t)64 * DP * 2);
  f16* WkLo = (f16*)carve((size_t)64 * DP * 2);
  float* Qpart = (float*)carve((size_t)16 * 524288 * 4);   // 32 MB
  (void)ws_size; (void)in_sizes; (void)n_in; (void)out_size;

  prep_flat<<<8208, 256, 0, stream>>>(obj_seq, flatA);
  prep_obj<<<2176, 256, 0, stream>>>(obj_seq, objHi, objLo, objT16);
  prep_wk<<<136, 256, 0, stream>>>(W_k, WkHi, WkLo);
  qgemm<<<256, 512, 0, stream>>>(flatA, W_q1, W_q2, Qpart);
  predinet_tail<<<128, 512, 0, stream>>>(objHi, objLo, objT16, WkHi, WkLo, Qpart, W_s, out);
}